// Round 1
// baseline (1211.966 us; speedup 1.0000x reference)
//
#include <hip/hip_runtime.h>
#include <cstddef>

#define EMBED 1024
#define HEADS 16
#define HDIM  64
#define BATCH 2
#define SEQ   2048
#define MTOT  (BATCH*SEQ)

// ---------------------------------------------------------------------------
// fp32 GEMM: C[M][N] = A[M][K] @ W[N][K]^T + bias[N]
// BM=BN=64, BK=32, 256 threads, 4x4 micro-tile.
// LDS tiles stored transposed [BK][BM+4] so the inner loop reads contiguous
// float4 (ds_read_b128) -> VALU-bound, not LDS-read-bound.
// ---------------------------------------------------------------------------
__global__ __launch_bounds__(256)
void gemm_nt_bias(const float* __restrict__ A, const float* __restrict__ W,
                  const float* __restrict__ bias, float* __restrict__ C,
                  int M, int N, int K)
{
    constexpr int BM = 64, BN = 64, BK = 32, PAD = 4;  // stride 68: 16B-aligned rows
    __shared__ float As[BK][BM + PAD];
    __shared__ float Ws[BK][BN + PAD];

    const int tid = threadIdx.x;
    const int tx = tid & 15;   // -> N
    const int ty = tid >> 4;   // -> M
    const int m0 = blockIdx.y * BM;
    const int n0 = blockIdx.x * BN;

    float acc[4][4] = {};

    for (int k0 = 0; k0 < K; k0 += BK) {
        __syncthreads();  // previous iteration's LDS reads complete
        #pragma unroll
        for (int t = 0; t < 2; ++t) {
            int idx = tid + t * 256;           // 0..511 float4 slots (64 rows x 8)
            int row = idx >> 3;
            int c4  = (idx & 7) << 2;
            float4 va = *(const float4*)(A + (size_t)(m0 + row) * K + k0 + c4);
            As[c4 + 0][row] = va.x;
            As[c4 + 1][row] = va.y;
            As[c4 + 2][row] = va.z;
            As[c4 + 3][row] = va.w;
            float4 vw = *(const float4*)(W + (size_t)(n0 + row) * K + k0 + c4);
            Ws[c4 + 0][row] = vw.x;
            Ws[c4 + 1][row] = vw.y;
            Ws[c4 + 2][row] = vw.z;
            Ws[c4 + 3][row] = vw.w;
        }
        __syncthreads();

        #pragma unroll
        for (int kk = 0; kk < BK; ++kk) {
            float4 a4 = *(const float4*)&As[kk][ty * 4];
            float4 b4 = *(const float4*)&Ws[kk][tx * 4];
            float av[4] = {a4.x, a4.y, a4.z, a4.w};
            float bv[4] = {b4.x, b4.y, b4.z, b4.w};
            #pragma unroll
            for (int i = 0; i < 4; ++i)
                #pragma unroll
                for (int j = 0; j < 4; ++j)
                    acc[i][j] = fmaf(av[i], bv[j], acc[i][j]);
        }
    }

    #pragma unroll
    for (int i = 0; i < 4; ++i) {
        int r = m0 + ty * 4 + i;
        #pragma unroll
        for (int j = 0; j < 4; ++j) {
            int c = n0 + tx * 4 + j;
            C[(size_t)r * N + c] = acc[i][j] + bias[c];
        }
    }
}

// ---------------------------------------------------------------------------
// Flash attention (fp32). One block = one (b, h, 64-row Q tile).
// q/k/v laid out as [B*S][E]; head h occupies cols h*64..h*64+63.
// Online softmax with running (m, l) per row; P*V accumulated in registers.
// ---------------------------------------------------------------------------
__global__ __launch_bounds__(256)
void flash_attn(const float* __restrict__ Q, const float* __restrict__ Km,
                const float* __restrict__ V, float* __restrict__ O)
{
    constexpr int TS = 64, PAD = 4;        // row stride 68 (16B aligned)
    __shared__ float Qs[HDIM][TS + PAD];   // [d][qrow]   (transposed)
    __shared__ float Ks[HDIM][TS + PAD];   // [d][krow]   (transposed)
    __shared__ float Vs[TS][HDIM + PAD];   // [krow][d]
    __shared__ float Ps[TS][TS + PAD];     // [krow][qrow] (transposed)

    const int tid = threadIdx.x;
    const int tx = tid & 15;   // -> k-cols of score tile / d-cols of O
    const int ty = tid >> 4;   // -> q-rows
    const int q0 = blockIdx.x * TS;
    const int h  = blockIdx.y;
    const int b  = blockIdx.z;

    const float* qb = Q  + (size_t)b * SEQ * EMBED + (size_t)h * HDIM;
    const float* kb = Km + (size_t)b * SEQ * EMBED + (size_t)h * HDIM;
    const float* vb = V  + (size_t)b * SEQ * EMBED + (size_t)h * HDIM;
    float*       ob = O  + (size_t)b * SEQ * EMBED + (size_t)h * HDIM;

    const float scale = 0.125f;  // 1/sqrt(64)

    // Load Q tile transposed and pre-scaled: Qs[d][row]
    #pragma unroll
    for (int t = 0; t < 4; ++t) {
        int idx = tid + t * 256;           // 0..1023 float4 slots (64 rows x 16)
        int row = idx >> 4;
        int c4  = (idx & 15) << 2;
        float4 vq = *(const float4*)(qb + (size_t)(q0 + row) * EMBED + c4);
        Qs[c4 + 0][row] = vq.x * scale;
        Qs[c4 + 1][row] = vq.y * scale;
        Qs[c4 + 2][row] = vq.z * scale;
        Qs[c4 + 3][row] = vq.w * scale;
    }

    float m_i[4], l_i[4];
    float accO[4][4] = {};
    #pragma unroll
    for (int i = 0; i < 4; ++i) { m_i[i] = -1e30f; l_i[i] = 0.f; }

    for (int kt = 0; kt < SEQ / TS; ++kt) {
        __syncthreads();   // prev-iter LDS reads done (also makes Qs visible at kt=0)
        const int kbase = kt * TS;
        #pragma unroll
        for (int t = 0; t < 4; ++t) {
            int idx = tid + t * 256;
            int row = idx >> 4;
            int c4  = (idx & 15) << 2;
            float4 vk = *(const float4*)(kb + (size_t)(kbase + row) * EMBED + c4);
            Ks[c4 + 0][row] = vk.x;
            Ks[c4 + 1][row] = vk.y;
            Ks[c4 + 2][row] = vk.z;
            Ks[c4 + 3][row] = vk.w;
            float4 vv = *(const float4*)(vb + (size_t)(kbase + row) * EMBED + c4);
            *(float4*)&Vs[row][c4] = vv;
        }
        __syncthreads();

        // scores s[i][j] = sum_d Qs[d][4ty+i] * Ks[d][4tx+j]   (Q pre-scaled)
        float s[4][4] = {};
        #pragma unroll
        for (int d = 0; d < HDIM; ++d) {
            float4 a4 = *(const float4*)&Qs[d][ty * 4];
            float4 b4 = *(const float4*)&Ks[d][tx * 4];
            float av[4] = {a4.x, a4.y, a4.z, a4.w};
            float bv[4] = {b4.x, b4.y, b4.z, b4.w};
            #pragma unroll
            for (int i = 0; i < 4; ++i)
                #pragma unroll
                for (int j = 0; j < 4; ++j)
                    s[i][j] = fmaf(av[i], bv[j], s[i][j]);
        }

        // online softmax; row group = 16 lanes sharing ty (shuffle over tx bits)
        #pragma unroll
        for (int i = 0; i < 4; ++i) {
            float mt = fmaxf(fmaxf(s[i][0], s[i][1]), fmaxf(s[i][2], s[i][3]));
            #pragma unroll
            for (int off = 1; off < 16; off <<= 1)
                mt = fmaxf(mt, __shfl_xor(mt, off, 64));
            float mnew  = fmaxf(m_i[i], mt);
            float alpha = __expf(m_i[i] - mnew);
            m_i[i] = mnew;
            float rs = 0.f;
            #pragma unroll
            for (int j = 0; j < 4; ++j) {
                s[i][j] = __expf(s[i][j] - mnew);
                rs += s[i][j];
            }
            #pragma unroll
            for (int off = 1; off < 16; off <<= 1)
                rs += __shfl_xor(rs, off, 64);
            l_i[i] = l_i[i] * alpha + rs;
            #pragma unroll
            for (int j = 0; j < 4; ++j)
                accO[i][j] *= alpha;
        }

        // write P transposed: Ps[krow][qrow]
        #pragma unroll
        for (int i = 0; i < 4; ++i)
            #pragma unroll
            for (int j = 0; j < 4; ++j)
                Ps[tx * 4 + j][ty * 4 + i] = s[i][j];
        __syncthreads();

        // accO[i][j] += sum_kk Ps[kk][4ty+i] * Vs[kk][4tx+j]
        #pragma unroll
        for (int kk = 0; kk < TS; ++kk) {
            float4 p4 = *(const float4*)&Ps[kk][ty * 4];
            float4 v4 = *(const float4*)&Vs[kk][tx * 4];
            float pv[4] = {p4.x, p4.y, p4.z, p4.w};
            float vv[4] = {v4.x, v4.y, v4.z, v4.w};
            #pragma unroll
            for (int i = 0; i < 4; ++i)
                #pragma unroll
                for (int j = 0; j < 4; ++j)
                    accO[i][j] = fmaf(pv[i], vv[j], accO[i][j]);
        }
    }

    #pragma unroll
    for (int i = 0; i < 4; ++i) {
        float inv = 1.f / l_i[i];
        int r = q0 + ty * 4 + i;
        #pragma unroll
        for (int j = 0; j < 4; ++j)
            ob[(size_t)r * EMBED + tx * 4 + j] = accO[i][j] * inv;
    }
}

// ---------------------------------------------------------------------------
extern "C" void kernel_launch(void* const* d_in, const int* in_sizes, int n_in,
                              void* d_out, int out_size, void* d_ws, size_t ws_size,
                              hipStream_t stream)
{
    const float* x  = (const float*)d_in[0];
    const float* Wq = (const float*)d_in[1];
    const float* bq = (const float*)d_in[2];
    const float* Wk = (const float*)d_in[3];
    const float* bk = (const float*)d_in[4];
    const float* Wv = (const float*)d_in[5];
    const float* bv = (const float*)d_in[6];
    const float* Wo = (const float*)d_in[7];
    const float* bo = (const float*)d_in[8];
    float* out = (float*)d_out;

    float* q    = (float*)d_ws;                       // [MTOT][EMBED]
    float* k    = q    + (size_t)MTOT * EMBED;
    float* v    = k    + (size_t)MTOT * EMBED;
    float* attn = v    + (size_t)MTOT * EMBED;        // 64 MB total

    dim3 blk(256);
    dim3 ggrid(EMBED / 64, MTOT / 64);                // 16 x 64 blocks

    gemm_nt_bias<<<ggrid, blk, 0, stream>>>(x, Wq, bq, q, MTOT, EMBED, EMBED);
    gemm_nt_bias<<<ggrid, blk, 0, stream>>>(x, Wk, bk, k, MTOT, EMBED, EMBED);
    gemm_nt_bias<<<ggrid, blk, 0, stream>>>(x, Wv, bv, v, MTOT, EMBED, EMBED);

    dim3 agrid(SEQ / 64, HEADS, BATCH);               // 32 x 16 x 2 blocks
    flash_attn<<<agrid, blk, 0, stream>>>(q, k, v, attn);

    gemm_nt_bias<<<ggrid, blk, 0, stream>>>(attn, Wo, bo, out, MTOT, EMBED, EMBED);
}

// Round 2
// 588.518 us; speedup vs baseline: 2.0594x; 2.0594x over previous
//
#include <hip/hip_runtime.h>
#include <cstddef>

#define EMBED 1024
#define HEADS 16
#define HDIM  64
#define BATCH 2
#define SEQ   2048
#define MTOT  (BATCH*SEQ)

typedef __attribute__((ext_vector_type(8))) short short8;  // 8 bf16 = 4 VGPRs
typedef __attribute__((ext_vector_type(4))) float f32x4;   // MFMA C/D frag

// fp32 -> bf16 round-to-nearest-even (bit trick; deterministic, no API deps)
static __device__ __forceinline__ unsigned short f2bf(float x) {
    unsigned u = __builtin_bit_cast(unsigned, x);
    unsigned r = (u + 0x7FFFu + ((u >> 16) & 1u)) >> 16;
    return (unsigned short)r;
}

// ---------------------------------------------------------------------------
// fp32 GEMM: C[M][N] = A[M][K] @ W[N][K]^T + bias[N]  (unchanged from R1)
// ---------------------------------------------------------------------------
__global__ __launch_bounds__(256)
void gemm_nt_bias(const float* __restrict__ A, const float* __restrict__ W,
                  const float* __restrict__ bias, float* __restrict__ C,
                  int M, int N, int K)
{
    constexpr int BM = 64, BN = 64, BK = 32, PAD = 4;
    __shared__ float As[BK][BM + PAD];
    __shared__ float Ws[BK][BN + PAD];

    const int tid = threadIdx.x;
    const int tx = tid & 15;
    const int ty = tid >> 4;
    const int m0 = blockIdx.y * BM;
    const int n0 = blockIdx.x * BN;

    float acc[4][4] = {};

    for (int k0 = 0; k0 < K; k0 += BK) {
        __syncthreads();
        #pragma unroll
        for (int t = 0; t < 2; ++t) {
            int idx = tid + t * 256;
            int row = idx >> 3;
            int c4  = (idx & 7) << 2;
            float4 va = *(const float4*)(A + (size_t)(m0 + row) * K + k0 + c4);
            As[c4 + 0][row] = va.x;
            As[c4 + 1][row] = va.y;
            As[c4 + 2][row] = va.z;
            As[c4 + 3][row] = va.w;
            float4 vw = *(const float4*)(W + (size_t)(n0 + row) * K + k0 + c4);
            Ws[c4 + 0][row] = vw.x;
            Ws[c4 + 1][row] = vw.y;
            Ws[c4 + 2][row] = vw.z;
            Ws[c4 + 3][row] = vw.w;
        }
        __syncthreads();

        #pragma unroll
        for (int kk = 0; kk < BK; ++kk) {
            float4 a4 = *(const float4*)&As[kk][ty * 4];
            float4 b4 = *(const float4*)&Ws[kk][tx * 4];
            float av[4] = {a4.x, a4.y, a4.z, a4.w};
            float bv[4] = {b4.x, b4.y, b4.z, b4.w};
            #pragma unroll
            for (int i = 0; i < 4; ++i)
                #pragma unroll
                for (int j = 0; j < 4; ++j)
                    acc[i][j] = fmaf(av[i], bv[j], acc[i][j]);
        }
    }

    #pragma unroll
    for (int i = 0; i < 4; ++i) {
        int r = m0 + ty * 4 + i;
        #pragma unroll
        for (int j = 0; j < 4; ++j) {
            int c = n0 + tx * 4 + j;
            C[(size_t)r * N + c] = acc[i][j] + bias[c];
        }
    }
}

// ---------------------------------------------------------------------------
// prep 1: Qb = bf16(q * 0.125)  [scale exact in bf16], Kb = bf16(k)
// ---------------------------------------------------------------------------
__global__ __launch_bounds__(256)
void conv_qk(const float* __restrict__ q, const float* __restrict__ k,
             unsigned short* __restrict__ Qb, unsigned short* __restrict__ Kb)
{
    int i = (blockIdx.x * 256 + threadIdx.x) * 4;
    float4 vq = *(const float4*)(q + i);
    float4 vk = *(const float4*)(k + i);
    ushort4 oq, ok;
    oq.x = f2bf(vq.x * 0.125f); oq.y = f2bf(vq.y * 0.125f);
    oq.z = f2bf(vq.z * 0.125f); oq.w = f2bf(vq.w * 0.125f);
    ok.x = f2bf(vk.x); ok.y = f2bf(vk.y); ok.z = f2bf(vk.z); ok.w = f2bf(vk.w);
    *(ushort4*)(Qb + i) = oq;
    *(ushort4*)(Kb + i) = ok;
}

// ---------------------------------------------------------------------------
// prep 2: Vt[b][h][d][s] = bf16(v[b*S+s][h*64+d])  (per-head transpose)
// ---------------------------------------------------------------------------
__global__ __launch_bounds__(256)
void conv_vt(const float* __restrict__ v, unsigned short* __restrict__ Vt)
{
    __shared__ float Ls[64][65];
    const int s0 = blockIdx.x * 64;
    const int h  = blockIdx.y;
    const int b  = blockIdx.z;
    const float* vb = v + (size_t)(b * SEQ + s0) * EMBED + h * HDIM;

    #pragma unroll
    for (int it = 0; it < 4; ++it) {
        int slot = threadIdx.x + it * 256;
        int r = slot >> 4, c4 = (slot & 15) << 2;
        float4 t = *(const float4*)(vb + (size_t)r * EMBED + c4);
        Ls[r][c4 + 0] = t.x; Ls[r][c4 + 1] = t.y;
        Ls[r][c4 + 2] = t.z; Ls[r][c4 + 3] = t.w;
    }
    __syncthreads();
    unsigned short* ob = Vt + ((size_t)(b * HEADS + h) * HDIM) * SEQ + s0;
    #pragma unroll
    for (int it = 0; it < 4; ++it) {
        int slot = threadIdx.x + it * 256;
        int d = slot >> 4, s4 = (slot & 15) << 2;
        ushort4 o;
        o.x = f2bf(Ls[s4 + 0][d]); o.y = f2bf(Ls[s4 + 1][d]);
        o.z = f2bf(Ls[s4 + 2][d]); o.w = f2bf(Ls[s4 + 3][d]);
        *(ushort4*)(ob + (size_t)d * SEQ + s4) = o;
    }
}

// ---------------------------------------------------------------------------
// MFMA flash attention. Block = (64 q-rows, h, b); 4 waves, wave w owns q rows
// [q0+16w, q0+16w+16). Per KV tile of 64:
//   St[kv][q] = K·Q^T  (A=K rows=kv, B=Q cols=q; C: col=lane&15=q,
//                       row=4*(lane>>4)+reg=kv  [m89-verified layout])
//   softmax over kv: 16 lane-local vals + shfl_xor(16,32)
//   P -> per-wave-private LDS (bf16) -> A-frags; out += P·V with B from Vt.
// All A/B frags packed with the same k-permutation (g*8+j) -> exact dot.
// ---------------------------------------------------------------------------
__global__ __launch_bounds__(256)
void flash_attn_mfma(const unsigned short* __restrict__ Qb,
                     const unsigned short* __restrict__ Kb,
                     const unsigned short* __restrict__ Vt,
                     float* __restrict__ O)
{
    constexpr int LDK = 72;              // padded row stride (bf16): 144 B, 16B-aligned
    __shared__ short Kh[64 * LDK];       // K tile  [kv][d]
    __shared__ short Vs[64 * LDK];       // V tile  [d][kv]   (from Vt)
    __shared__ short Pq[4 * 16 * LDK];   // per-wave P [16 q][64 kv]

    const int tid  = threadIdx.x;
    const int lane = tid & 63;
    const int w    = tid >> 6;
    const int c    = lane & 15;          // col index (q for St; d for out)
    const int g    = lane >> 4;          // k-group
    const int q0   = blockIdx.x * 64;
    const int h    = blockIdx.y;
    const int b    = blockIdx.z;

    // Q B-frags (persistent): col=q=c, k=d = ks*32 + g*8 + j
    const size_t rowQ = (size_t)(b * SEQ + q0 + w * 16 + c) * EMBED + h * HDIM;
    short8 qf0 = *(const short8*)(Qb + rowQ + g * 8);
    short8 qf1 = *(const short8*)(Qb + rowQ + 32 + g * 8);

    const unsigned short* kbase = Kb + (size_t)(b * SEQ) * EMBED + h * HDIM;
    const unsigned short* vbase = Vt + ((size_t)(b * HEADS + h) * HDIM) * SEQ;

    f32x4 acc_o[4] = {};                 // out[q=4g+reg][d=16dt+c]
    float m_run = -1e30f, l_run = 0.f;   // state for q = c (replicated over g)

    for (int kt = 0; kt < SEQ / 64; ++kt) {
        __syncthreads();                 // prev iter's K/V reads complete
        const int kv0 = kt * 64;
        // stage K and V tiles: 512 slots x 8 bf16 (16 B)
        #pragma unroll
        for (int it = 0; it < 2; ++it) {
            int slot = tid + it * 256;
            int r = slot >> 3, c8 = (slot & 7) << 3;
            *(uint4*)&Kh[r * LDK + c8] =
                *(const uint4*)(kbase + (size_t)(kv0 + r) * EMBED + c8);
            *(uint4*)&Vs[r * LDK + c8] =
                *(const uint4*)(vbase + (size_t)r * SEQ + kv0 + c8);
        }
        __syncthreads();

        // QK^T: St[kv][q], 4 kv-subtiles
        f32x4 sacc[4] = {};
        #pragma unroll
        for (int t = 0; t < 4; ++t) {
            short8 ka0 = *(const short8*)&Kh[(t * 16 + c) * LDK + g * 8];
            short8 ka1 = *(const short8*)&Kh[(t * 16 + c) * LDK + 32 + g * 8];
            sacc[t] = __builtin_amdgcn_mfma_f32_16x16x32_bf16(ka0, qf0, sacc[t], 0, 0, 0);
            sacc[t] = __builtin_amdgcn_mfma_f32_16x16x32_bf16(ka1, qf1, sacc[t], 0, 0, 0);
        }

        // online softmax over kv for q=c: lane holds kv = 16t + 4g + reg
        float mt = -1e30f;
        #pragma unroll
        for (int t = 0; t < 4; ++t)
            #pragma unroll
            for (int r = 0; r < 4; ++r)
                mt = fmaxf(mt, sacc[t][r]);
        mt = fmaxf(mt, __shfl_xor(mt, 16, 64));
        mt = fmaxf(mt, __shfl_xor(mt, 32, 64));
        float mnew  = fmaxf(m_run, mt);
        float alpha = __expf(m_run - mnew);
        m_run = mnew;

        float rs = 0.f;
        ushort4 pk[4];
        #pragma unroll
        for (int t = 0; t < 4; ++t) {
            float p0 = __expf(sacc[t][0] - mnew);
            float p1 = __expf(sacc[t][1] - mnew);
            float p2 = __expf(sacc[t][2] - mnew);
            float p3 = __expf(sacc[t][3] - mnew);
            rs += (p0 + p1) + (p2 + p3);
            pk[t].x = f2bf(p0); pk[t].y = f2bf(p1);
            pk[t].z = f2bf(p2); pk[t].w = f2bf(p3);
        }
        rs += __shfl_xor(rs, 16, 64);
        rs += __shfl_xor(rs, 32, 64);
        l_run = l_run * alpha + rs;

        // write P (wave-private region; DS in-order per wave, no barrier)
        short* pw = &Pq[w * 16 * LDK];
        #pragma unroll
        for (int t = 0; t < 4; ++t)
            *(ushort4*)&pw[c * LDK + t * 16 + g * 4] = pk[t];

        // rescale accumulated O by alpha of rows q' = 4g + r
        #pragma unroll
        for (int r = 0; r < 4; ++r) {
            float af = __shfl(alpha, g * 4 + r, 64);
            #pragma unroll
            for (int dt = 0; dt < 4; ++dt)
                acc_o[dt][r] *= af;
        }

        asm volatile("" ::: "memory");   // keep P reads after P writes (compile-time)

        // PV: A = P (row=q=c, k=kv), B = Vs (col=d, k=kv)
        short8 pa0 = *(const short8*)&pw[c * LDK + g * 8];
        short8 pa1 = *(const short8*)&pw[c * LDK + 32 + g * 8];
        #pragma unroll
        for (int dt = 0; dt < 4; ++dt) {
            short8 vb0 = *(const short8*)&Vs[(dt * 16 + c) * LDK + g * 8];
            short8 vb1 = *(const short8*)&Vs[(dt * 16 + c) * LDK + 32 + g * 8];
            acc_o[dt] = __builtin_amdgcn_mfma_f32_16x16x32_bf16(pa0, vb0, acc_o[dt], 0, 0, 0);
            acc_o[dt] = __builtin_amdgcn_mfma_f32_16x16x32_bf16(pa1, vb1, acc_o[dt], 0, 0, 0);
        }
    }

    // epilogue: divide by l and store (row q'=4g+r needs l of that row)
    float rl = 1.f / l_run;
    const size_t obase = (size_t)(b * SEQ + q0 + w * 16) * EMBED + h * HDIM;
    #pragma unroll
    for (int r = 0; r < 4; ++r) {
        float rf = __shfl(rl, g * 4 + r, 64);
        #pragma unroll
        for (int dt = 0; dt < 4; ++dt)
            O[obase + (size_t)(g * 4 + r) * EMBED + dt * 16 + c] = acc_o[dt][r] * rf;
    }
}

// ---------------------------------------------------------------------------
extern "C" void kernel_launch(void* const* d_in, const int* in_sizes, int n_in,
                              void* d_out, int out_size, void* d_ws, size_t ws_size,
                              hipStream_t stream)
{
    const float* x  = (const float*)d_in[0];
    const float* Wq = (const float*)d_in[1];
    const float* bq = (const float*)d_in[2];
    const float* Wk = (const float*)d_in[3];
    const float* bk = (const float*)d_in[4];
    const float* Wv = (const float*)d_in[5];
    const float* bv = (const float*)d_in[6];
    const float* Wo = (const float*)d_in[7];
    const float* bo = (const float*)d_in[8];
    float* out = (float*)d_out;

    // ws layout (64 MB total, same footprint as R1):
    //  [0..16M)  q fp32, later reused as attn fp32 (q dead after conv_qk)
    //  [16..32M) k fp32, later reused as Vt bf16 (k dead after conv_qk)
    //  [32..48M) v fp32
    //  [48..64M) Qb bf16 (8 MB) + Kb bf16 (8 MB)
    float* q = (float*)d_ws;
    float* k = q + (size_t)MTOT * EMBED;
    float* v = k + (size_t)MTOT * EMBED;
    unsigned short* Qb = (unsigned short*)(v + (size_t)MTOT * EMBED);
    unsigned short* Kb = Qb + (size_t)MTOT * EMBED;
    unsigned short* Vt = (unsigned short*)k;   // overwrites dead k fp32
    float* attn = q;                           // overwrites dead q fp32

    dim3 blk(256);
    dim3 ggrid(EMBED / 64, MTOT / 64);

    gemm_nt_bias<<<ggrid, blk, 0, stream>>>(x, Wq, bq, q, MTOT, EMBED, EMBED);
    gemm_nt_bias<<<ggrid, blk, 0, stream>>>(x, Wk, bk, k, MTOT, EMBED, EMBED);
    gemm_nt_bias<<<ggrid, blk, 0, stream>>>(x, Wv, bv, v, MTOT, EMBED, EMBED);

    conv_qk<<<dim3(MTOT * EMBED / 1024), blk, 0, stream>>>(q, k, Qb, Kb);
    conv_vt<<<dim3(SEQ / 64, HEADS, BATCH), blk, 0, stream>>>(v, Vt);

    flash_attn_mfma<<<dim3(SEQ / 64, HEADS, BATCH), blk, 0, stream>>>(Qb, Kb, Vt, attn);

    gemm_nt_bias<<<ggrid, blk, 0, stream>>>(attn, Wo, bo, out, MTOT, EMBED, EMBED);
}

// Round 3
// 165.178 us; speedup vs baseline: 7.3373x; 3.5629x over previous
//
#include <hip/hip_runtime.h>
#include <cstddef>

#define EMBED 1024
#define HEADS 16
#define HDIM  64
#define BATCH 2
#define SEQ   2048
#define MTOT  (BATCH*SEQ)

typedef __attribute__((ext_vector_type(8))) short short8;  // 8 bf16 = 4 VGPRs
typedef __attribute__((ext_vector_type(4))) float f32x4;   // MFMA C/D frag

typedef __attribute__((address_space(1))) const unsigned int* gas_u32p;
typedef __attribute__((address_space(3))) unsigned int* las_u32p;

// async global->LDS, 16B per lane; LDS dest = wave-uniform base + lane*16
static __device__ __forceinline__ void gload_lds16(const void* g, void* l) {
    __builtin_amdgcn_global_load_lds((gas_u32p)g, (las_u32p)l, 16, 0, 0);
}

// fp32 -> bf16 round-to-nearest-even
static __device__ __forceinline__ unsigned short f2bf(float x) {
    unsigned u = __builtin_bit_cast(unsigned, x);
    unsigned r = (u + 0x7FFFu + ((u >> 16) & 1u)) >> 16;
    return (unsigned short)r;
}

// ---------------------------------------------------------------------------
// convx: x fp32 -> bf16 (8 elems/thread)
// ---------------------------------------------------------------------------
__global__ __launch_bounds__(256)
void convx(const float* __restrict__ x, unsigned short* __restrict__ xh)
{
    const size_t i = ((size_t)blockIdx.x * 256 + threadIdx.x) * 8;
    float4 a = *(const float4*)(x + i);
    float4 b = *(const float4*)(x + i + 4);
    unsigned short o[8] __attribute__((aligned(16)));
    o[0] = f2bf(a.x); o[1] = f2bf(a.y); o[2] = f2bf(a.z); o[3] = f2bf(a.w);
    o[4] = f2bf(b.x); o[5] = f2bf(b.y); o[6] = f2bf(b.z); o[7] = f2bf(b.w);
    *(uint4*)(xh + i) = *(const uint4*)o;
}

// ---------------------------------------------------------------------------
// convw: {Wq,Wk,Wv,Wo} fp32 -> packed bf16 Wh[sel][1M]
// ---------------------------------------------------------------------------
__global__ __launch_bounds__(256)
void convw(const float* __restrict__ Wq, const float* __restrict__ Wk,
           const float* __restrict__ Wv, const float* __restrict__ Wo,
           unsigned short* __restrict__ Wh)
{
    const int sel = blockIdx.y;
    const float* src = sel == 0 ? Wq : sel == 1 ? Wk : sel == 2 ? Wv : Wo;
    unsigned short* dst = Wh + (size_t)sel * EMBED * EMBED;
    const size_t i = ((size_t)blockIdx.x * 256 + threadIdx.x) * 4;
    float4 a = *(const float4*)(src + i);
    ushort4 o;
    o.x = f2bf(a.x); o.y = f2bf(a.y); o.z = f2bf(a.z); o.w = f2bf(a.w);
    *(ushort4*)(dst + i) = o;
}

// ---------------------------------------------------------------------------
// Fused QKV GEMM (bf16 MFMA, m97-style): C = A @ W^T + b, bf16 out.
// BM=BN=128, BK=32, 4 waves (2x2), 4x4 frags/wave, global_load_lds w=16.
// blockIdx.x in [0,24): wsel = bx>>3 selects {Q,K,V}; n0 = (bx&7)*128.
// MFMA conventions identical to the R2-verified attention kernel:
//   A-frag lane(c,g): A[row=c][k=g*8..]; B-frag: B[col=c][k=g*8..]
//   C: [row=4g+r][col=c]
// ---------------------------------------------------------------------------
__global__ __launch_bounds__(256)
void gemm_qkv_bf16(const unsigned short* __restrict__ A,
                   const unsigned short* __restrict__ Wqh,
                   const unsigned short* __restrict__ Wkh,
                   const unsigned short* __restrict__ Wvh,
                   const float* __restrict__ bq,
                   const float* __restrict__ bk,
                   const float* __restrict__ bv,
                   unsigned short* __restrict__ Qb,
                   unsigned short* __restrict__ Kb,
                   unsigned short* __restrict__ Vb)
{
    __shared__ short As[128 * 32];   // [row][k] linear, 64 B/row (gload_lds needs linear)
    __shared__ short Bs[128 * 32];

    const int tid  = threadIdx.x;
    const int lane = tid & 63;
    const int w    = tid >> 6;
    const int c    = lane & 15;
    const int g    = lane >> 4;
    const int wr   = w >> 1;
    const int wc   = w & 1;

    const int m0   = blockIdx.y * 128;
    const int bx   = blockIdx.x;
    const int wsel = bx >> 3;
    const int n0   = (bx & 7) * 128;

    const unsigned short* W = (wsel == 0) ? Wqh : (wsel == 1) ? Wkh : Wvh;
    const float* bias       = (wsel == 0) ? bq  : (wsel == 1) ? bk  : bv;
    unsigned short* Out     = (wsel == 0) ? Qb  : (wsel == 1) ? Kb  : Vb;
    const float oscale      = (wsel == 0) ? 0.125f : 1.0f;

    f32x4 acc[4][4] = {};

    for (int k0 = 0; k0 < EMBED; k0 += 32) {
        __syncthreads();                         // prev-iter LDS reads done
        #pragma unroll
        for (int i = 0; i < 2; ++i) {            // 8 KB per tile = 2 issues/wave
            int s   = (w * 2 + i) * 64 + lane;   // 16B slot: row = s>>2, k8 = (s&3)*8
            int row = s >> 2;
            int k8  = (s & 3) * 8;
            gload_lds16(A + (size_t)(m0 + row) * EMBED + k0 + k8,
                        As + (size_t)(w * 2 + i) * 512);
            gload_lds16(W + (size_t)(n0 + row) * EMBED + k0 + k8,
                        Bs + (size_t)(w * 2 + i) * 512);
        }
        __syncthreads();                         // compiler drains vmcnt(0) here

        short8 af[4], bf[4];
        #pragma unroll
        for (int mi = 0; mi < 4; ++mi)
            af[mi] = *(const short8*)&As[(wr * 64 + mi * 16 + c) * 32 + g * 8];
        #pragma unroll
        for (int ni = 0; ni < 4; ++ni)
            bf[ni] = *(const short8*)&Bs[(wc * 64 + ni * 16 + c) * 32 + g * 8];
        #pragma unroll
        for (int mi = 0; mi < 4; ++mi)
            #pragma unroll
            for (int ni = 0; ni < 4; ++ni)
                acc[mi][ni] = __builtin_amdgcn_mfma_f32_16x16x32_bf16(
                    af[mi], bf[ni], acc[mi][ni], 0, 0, 0);
    }

    #pragma unroll
    for (int mi = 0; mi < 4; ++mi)
        #pragma unroll
        for (int r = 0; r < 4; ++r) {
            const int m = m0 + wr * 64 + mi * 16 + g * 4 + r;
            #pragma unroll
            for (int ni = 0; ni < 4; ++ni) {
                const int col = n0 + wc * 64 + ni * 16 + c;
                Out[(size_t)m * EMBED + col] =
                    f2bf((acc[mi][ni][r] + bias[col]) * oscale);
            }
        }
}

// ---------------------------------------------------------------------------
// Output GEMM: C = attn @ Wo^T + bo, fp32 out. BM=128, BN=64 (512 blocks).
// ---------------------------------------------------------------------------
__global__ __launch_bounds__(256)
void gemm_o_bf16(const unsigned short* __restrict__ A,
                 const unsigned short* __restrict__ Woh,
                 const float* __restrict__ bo,
                 float* __restrict__ C)
{
    __shared__ short As[128 * 32];
    __shared__ short Bs[64 * 32];

    const int tid  = threadIdx.x;
    const int lane = tid & 63;
    const int w    = tid >> 6;
    const int c    = lane & 15;
    const int g    = lane >> 4;
    const int wr   = w >> 1;
    const int wc   = w & 1;

    const int m0 = blockIdx.y * 128;
    const int n0 = blockIdx.x * 64;

    f32x4 acc[4][2] = {};

    for (int k0 = 0; k0 < EMBED; k0 += 32) {
        __syncthreads();
        #pragma unroll
        for (int i = 0; i < 2; ++i) {            // A: 8 KB = 2 issues/wave
            int s   = (w * 2 + i) * 64 + lane;
            int row = s >> 2;
            int k8  = (s & 3) * 8;
            gload_lds16(A + (size_t)(m0 + row) * EMBED + k0 + k8,
                        As + (size_t)(w * 2 + i) * 512);
        }
        {                                        // B: 4 KB = 1 issue/wave
            int s   = w * 64 + lane;
            int row = s >> 2;
            int k8  = (s & 3) * 8;
            gload_lds16(Woh + (size_t)(n0 + row) * EMBED + k0 + k8,
                        Bs + (size_t)w * 512);
        }
        __syncthreads();

        short8 af[4], bf[2];
        #pragma unroll
        for (int mi = 0; mi < 4; ++mi)
            af[mi] = *(const short8*)&As[(wr * 64 + mi * 16 + c) * 32 + g * 8];
        #pragma unroll
        for (int ni = 0; ni < 2; ++ni)
            bf[ni] = *(const short8*)&Bs[(wc * 32 + ni * 16 + c) * 32 + g * 8];
        #pragma unroll
        for (int mi = 0; mi < 4; ++mi)
            #pragma unroll
            for (int ni = 0; ni < 2; ++ni)
                acc[mi][ni] = __builtin_amdgcn_mfma_f32_16x16x32_bf16(
                    af[mi], bf[ni], acc[mi][ni], 0, 0, 0);
    }

    #pragma unroll
    for (int mi = 0; mi < 4; ++mi)
        #pragma unroll
        for (int r = 0; r < 4; ++r) {
            const int m = m0 + wr * 64 + mi * 16 + g * 4 + r;
            #pragma unroll
            for (int ni = 0; ni < 2; ++ni) {
                const int col = n0 + wc * 32 + ni * 16 + c;
                C[(size_t)m * EMBED + col] = acc[mi][ni][r] + bo[col];
            }
        }
}

// ---------------------------------------------------------------------------
// conv_vt: Vb bf16 [B*S][E] -> Vt bf16 [b][h][d][s] (per-head transpose)
// ---------------------------------------------------------------------------
__global__ __launch_bounds__(256)
void conv_vt_bf16(const unsigned short* __restrict__ Vb,
                  unsigned short* __restrict__ Vt)
{
    __shared__ unsigned short Ls[64][72];
    const int s0 = blockIdx.x * 64;
    const int h  = blockIdx.y;
    const int b  = blockIdx.z;
    const unsigned short* src = Vb + (size_t)(b * SEQ + s0) * EMBED + h * HDIM;

    #pragma unroll
    for (int it = 0; it < 2; ++it) {
        int slot = threadIdx.x + it * 256;     // 0..511: 64 rows x 8 slots
        int r = slot >> 3, c8 = (slot & 7) * 8;
        *(uint4*)&Ls[r][c8] = *(const uint4*)(src + (size_t)r * EMBED + c8);
    }
    __syncthreads();
    unsigned short* dst = Vt + ((size_t)(b * HEADS + h) * HDIM) * SEQ + s0;
    #pragma unroll
    for (int it = 0; it < 2; ++it) {
        int slot = threadIdx.x + it * 256;
        int d = slot >> 3, s8 = (slot & 7) * 8;
        unsigned short tmp[8] __attribute__((aligned(16)));
        #pragma unroll
        for (int j = 0; j < 8; ++j) tmp[j] = Ls[s8 + j][d];
        *(uint4*)(dst + (size_t)d * SEQ + s8) = *(const uint4*)tmp;
    }
}

// ---------------------------------------------------------------------------
// MFMA flash attention (unchanged core from R2; output now bf16)
// ---------------------------------------------------------------------------
__global__ __launch_bounds__(256)
void flash_attn_mfma(const unsigned short* __restrict__ Qb,
                     const unsigned short* __restrict__ Kb,
                     const unsigned short* __restrict__ Vt,
                     unsigned short* __restrict__ O)
{
    constexpr int LDK = 72;
    __shared__ short Kh[64 * LDK];
    __shared__ short Vs[64 * LDK];
    __shared__ short Pq[4 * 16 * LDK];

    const int tid  = threadIdx.x;
    const int lane = tid & 63;
    const int w    = tid >> 6;
    const int c    = lane & 15;
    const int g    = lane >> 4;
    const int q0   = blockIdx.x * 64;
    const int h    = blockIdx.y;
    const int b    = blockIdx.z;

    const size_t rowQ = (size_t)(b * SEQ + q0 + w * 16 + c) * EMBED + h * HDIM;
    short8 qf0 = *(const short8*)(Qb + rowQ + g * 8);
    short8 qf1 = *(const short8*)(Qb + rowQ + 32 + g * 8);

    const unsigned short* kbase = Kb + (size_t)(b * SEQ) * EMBED + h * HDIM;
    const unsigned short* vbase = Vt + ((size_t)(b * HEADS + h) * HDIM) * SEQ;

    f32x4 acc_o[4] = {};
    float m_run = -1e30f, l_run = 0.f;

    for (int kt = 0; kt < SEQ / 64; ++kt) {
        __syncthreads();
        const int kv0 = kt * 64;
        #pragma unroll
        for (int it = 0; it < 2; ++it) {
            int slot = tid + it * 256;
            int r = slot >> 3, c8 = (slot & 7) << 3;
            *(uint4*)&Kh[r * LDK + c8] =
                *(const uint4*)(kbase + (size_t)(kv0 + r) * EMBED + c8);
            *(uint4*)&Vs[r * LDK + c8] =
                *(const uint4*)(vbase + (size_t)r * SEQ + kv0 + c8);
        }
        __syncthreads();

        f32x4 sacc[4] = {};
        #pragma unroll
        for (int t = 0; t < 4; ++t) {
            short8 ka0 = *(const short8*)&Kh[(t * 16 + c) * LDK + g * 8];
            short8 ka1 = *(const short8*)&Kh[(t * 16 + c) * LDK + 32 + g * 8];
            sacc[t] = __builtin_amdgcn_mfma_f32_16x16x32_bf16(ka0, qf0, sacc[t], 0, 0, 0);
            sacc[t] = __builtin_amdgcn_mfma_f32_16x16x32_bf16(ka1, qf1, sacc[t], 0, 0, 0);
        }

        float mt = -1e30f;
        #pragma unroll
        for (int t = 0; t < 4; ++t)
            #pragma unroll
            for (int r = 0; r < 4; ++r)
                mt = fmaxf(mt, sacc[t][r]);
        mt = fmaxf(mt, __shfl_xor(mt, 16, 64));
        mt = fmaxf(mt, __shfl_xor(mt, 32, 64));
        float mnew  = fmaxf(m_run, mt);
        float alpha = __expf(m_run - mnew);
        m_run = mnew;

        float rs = 0.f;
        ushort4 pk[4];
        #pragma unroll
        for (int t = 0; t < 4; ++t) {
            float p0 = __expf(sacc[t][0] - mnew);
            float p1 = __expf(sacc[t][1] - mnew);
            float p2 = __expf(sacc[t][2] - mnew);
            float p3 = __expf(sacc[t][3] - mnew);
            rs += (p0 + p1) + (p2 + p3);
            pk[t].x = f2bf(p0); pk[t].y = f2bf(p1);
            pk[t].z = f2bf(p2); pk[t].w = f2bf(p3);
        }
        rs += __shfl_xor(rs, 16, 64);
        rs += __shfl_xor(rs, 32, 64);
        l_run = l_run * alpha + rs;

        short* pw = &Pq[w * 16 * LDK];
        #pragma unroll
        for (int t = 0; t < 4; ++t)
            *(ushort4*)&pw[c * LDK + t * 16 + g * 4] = pk[t];

        #pragma unroll
        for (int r = 0; r < 4; ++r) {
            float af = __shfl(alpha, g * 4 + r, 64);
            #pragma unroll
            for (int dt = 0; dt < 4; ++dt)
                acc_o[dt][r] *= af;
        }

        asm volatile("" ::: "memory");

        short8 pa0 = *(const short8*)&pw[c * LDK + g * 8];
        short8 pa1 = *(const short8*)&pw[c * LDK + 32 + g * 8];
        #pragma unroll
        for (int dt = 0; dt < 4; ++dt) {
            short8 vb0 = *(const short8*)&Vs[(dt * 16 + c) * LDK + g * 8];
            short8 vb1 = *(const short8*)&Vs[(dt * 16 + c) * LDK + 32 + g * 8];
            acc_o[dt] = __builtin_amdgcn_mfma_f32_16x16x32_bf16(pa0, vb0, acc_o[dt], 0, 0, 0);
            acc_o[dt] = __builtin_amdgcn_mfma_f32_16x16x32_bf16(pa1, vb1, acc_o[dt], 0, 0, 0);
        }
    }

    float rl = 1.f / l_run;
    const size_t obase = (size_t)(b * SEQ + q0 + w * 16) * EMBED + h * HDIM;
    #pragma unroll
    for (int r = 0; r < 4; ++r) {
        float rf = __shfl(rl, g * 4 + r, 64);
        #pragma unroll
        for (int dt = 0; dt < 4; ++dt)
            O[obase + (size_t)(g * 4 + r) * EMBED + dt * 16 + c] =
                f2bf(acc_o[dt][r] * rf);
    }
}

// ---------------------------------------------------------------------------
extern "C" void kernel_launch(void* const* d_in, const int* in_sizes, int n_in,
                              void* d_out, int out_size, void* d_ws, size_t ws_size,
                              hipStream_t stream)
{
    const float* x  = (const float*)d_in[0];
    const float* Wq = (const float*)d_in[1];
    const float* bq = (const float*)d_in[2];
    const float* Wk = (const float*)d_in[3];
    const float* bk = (const float*)d_in[4];
    const float* Wv = (const float*)d_in[5];
    const float* bv = (const float*)d_in[6];
    const float* Wo = (const float*)d_in[7];
    const float* bo = (const float*)d_in[8];
    float* out = (float*)d_out;

    // ws layout (bf16 elements; 56 MB total):
    const size_t ME = (size_t)MTOT * EMBED;           // 4M elems
    unsigned short* xh   = (unsigned short*)d_ws;     // 8 MB
    unsigned short* Qb   = xh   + ME;
    unsigned short* Kb   = Qb   + ME;
    unsigned short* Vb   = Kb   + ME;
    unsigned short* Vt   = Vb   + ME;
    unsigned short* attn = Vt   + ME;
    unsigned short* Wh   = attn + ME;                 // 4 x 2 MB packed

    dim3 blk(256);

    convx<<<dim3(MTOT * EMBED / 2048), blk, 0, stream>>>(x, xh);
    convw<<<dim3(EMBED * EMBED / 1024, 4), blk, 0, stream>>>(Wq, Wk, Wv, Wo, Wh);

    gemm_qkv_bf16<<<dim3(24, MTOT / 128), blk, 0, stream>>>(
        xh, Wh, Wh + (size_t)EMBED * EMBED, Wh + 2 * (size_t)EMBED * EMBED,
        bq, bk, bv, Qb, Kb, Vb);

    conv_vt_bf16<<<dim3(SEQ / 64, HEADS, BATCH), blk, 0, stream>>>(Vb, Vt);

    flash_attn_mfma<<<dim3(SEQ / 64, HEADS, BATCH), blk, 0, stream>>>(Qb, Kb, Vt, attn);

    gemm_o_bf16<<<dim3(EMBED / 64, MTOT / 128), blk, 0, stream>>>(
        attn, Wh + 3 * (size_t)EMBED * EMBED, bo, out);
}

// Round 4
// 138.839 us; speedup vs baseline: 8.7293x; 1.1897x over previous
//
#include <hip/hip_runtime.h>
#include <cstddef>

#define EMBED 1024
#define HEADS 16
#define HDIM  64
#define BATCH 2
#define SEQ   2048
#define MTOT  (BATCH*SEQ)

typedef __attribute__((ext_vector_type(8))) short short8;  // 8 bf16 = 4 VGPRs
typedef __attribute__((ext_vector_type(4))) float f32x4;   // MFMA C/D frag

typedef __attribute__((address_space(1))) const unsigned int* gas_u32p;
typedef __attribute__((address_space(3))) unsigned int* las_u32p;

// async global->LDS, 16B per lane; LDS dest = wave-uniform base + lane*16
static __device__ __forceinline__ void gload_lds16(const void* g, void* l) {
    __builtin_amdgcn_global_load_lds((gas_u32p)g, (las_u32p)l, 16, 0, 0);
}

// fp32 -> bf16 round-to-nearest-even
static __device__ __forceinline__ unsigned short f2bf(float x) {
    unsigned u = __builtin_bit_cast(unsigned, x);
    unsigned r = (u + 0x7FFFu + ((u >> 16) & 1u)) >> 16;
    return (unsigned short)r;
}

// pack two fp32 -> one u32 of 2 bf16 (hardware cvt; m214-v22 verified on gfx950)
static __device__ __forceinline__ unsigned pk_bf16(float lo, float hi) {
    unsigned r;
    asm("v_cvt_pk_bf16_f32 %0, %1, %2" : "=v"(r) : "v"(lo), "v"(hi));
    return r;
}

// ---------------------------------------------------------------------------
// convx: x fp32 -> bf16 (8 elems/thread)
// ---------------------------------------------------------------------------
__global__ __launch_bounds__(256)
void convx(const float* __restrict__ x, unsigned short* __restrict__ xh)
{
    const size_t i = ((size_t)blockIdx.x * 256 + threadIdx.x) * 8;
    float4 a = *(const float4*)(x + i);
    float4 b = *(const float4*)(x + i + 4);
    unsigned short o[8] __attribute__((aligned(16)));
    o[0] = f2bf(a.x); o[1] = f2bf(a.y); o[2] = f2bf(a.z); o[3] = f2bf(a.w);
    o[4] = f2bf(b.x); o[5] = f2bf(b.y); o[6] = f2bf(b.z); o[7] = f2bf(b.w);
    *(uint4*)(xh + i) = *(const uint4*)o;
}

// ---------------------------------------------------------------------------
// convw: {Wq,Wk,Wv,Wo} fp32 -> packed bf16 Wh[sel][1M]
// ---------------------------------------------------------------------------
__global__ __launch_bounds__(256)
void convw(const float* __restrict__ Wq, const float* __restrict__ Wk,
           const float* __restrict__ Wv, const float* __restrict__ Wo,
           unsigned short* __restrict__ Wh)
{
    const int sel = blockIdx.y;
    const float* src = sel == 0 ? Wq : sel == 1 ? Wk : sel == 2 ? Wv : Wo;
    unsigned short* dst = Wh + (size_t)sel * EMBED * EMBED;
    const size_t i = ((size_t)blockIdx.x * 256 + threadIdx.x) * 4;
    float4 a = *(const float4*)(src + i);
    ushort4 o;
    o.x = f2bf(a.x); o.y = f2bf(a.y); o.z = f2bf(a.z); o.w = f2bf(a.w);
    *(ushort4*)(dst + i) = o;
}

// ---------------------------------------------------------------------------
// Fused QKV GEMM (bf16 MFMA, m97-style) — unchanged from R3
// ---------------------------------------------------------------------------
__global__ __launch_bounds__(256)
void gemm_qkv_bf16(const unsigned short* __restrict__ A,
                   const unsigned short* __restrict__ Wqh,
                   const unsigned short* __restrict__ Wkh,
                   const unsigned short* __restrict__ Wvh,
                   const float* __restrict__ bq,
                   const float* __restrict__ bk,
                   const float* __restrict__ bv,
                   unsigned short* __restrict__ Qb,
                   unsigned short* __restrict__ Kb,
                   unsigned short* __restrict__ Vb)
{
    __shared__ short As[128 * 32];
    __shared__ short Bs[128 * 32];

    const int tid  = threadIdx.x;
    const int lane = tid & 63;
    const int w    = tid >> 6;
    const int c    = lane & 15;
    const int g    = lane >> 4;
    const int wr   = w >> 1;
    const int wc   = w & 1;

    const int m0   = blockIdx.y * 128;
    const int bx   = blockIdx.x;
    const int wsel = bx >> 3;
    const int n0   = (bx & 7) * 128;

    const unsigned short* W = (wsel == 0) ? Wqh : (wsel == 1) ? Wkh : Wvh;
    const float* bias       = (wsel == 0) ? bq  : (wsel == 1) ? bk  : bv;
    unsigned short* Out     = (wsel == 0) ? Qb  : (wsel == 1) ? Kb  : Vb;
    const float oscale      = (wsel == 0) ? 0.125f : 1.0f;

    f32x4 acc[4][4] = {};

    for (int k0 = 0; k0 < EMBED; k0 += 32) {
        __syncthreads();
        #pragma unroll
        for (int i = 0; i < 2; ++i) {
            int s   = (w * 2 + i) * 64 + lane;
            int row = s >> 2;
            int k8  = (s & 3) * 8;
            gload_lds16(A + (size_t)(m0 + row) * EMBED + k0 + k8,
                        As + (size_t)(w * 2 + i) * 512);
            gload_lds16(W + (size_t)(n0 + row) * EMBED + k0 + k8,
                        Bs + (size_t)(w * 2 + i) * 512);
        }
        __syncthreads();

        short8 af[4], bf[4];
        #pragma unroll
        for (int mi = 0; mi < 4; ++mi)
            af[mi] = *(const short8*)&As[(wr * 64 + mi * 16 + c) * 32 + g * 8];
        #pragma unroll
        for (int ni = 0; ni < 4; ++ni)
            bf[ni] = *(const short8*)&Bs[(wc * 64 + ni * 16 + c) * 32 + g * 8];
        #pragma unroll
        for (int mi = 0; mi < 4; ++mi)
            #pragma unroll
            for (int ni = 0; ni < 4; ++ni)
                acc[mi][ni] = __builtin_amdgcn_mfma_f32_16x16x32_bf16(
                    af[mi], bf[ni], acc[mi][ni], 0, 0, 0);
    }

    #pragma unroll
    for (int mi = 0; mi < 4; ++mi)
        #pragma unroll
        for (int r = 0; r < 4; ++r) {
            const int m = m0 + wr * 64 + mi * 16 + g * 4 + r;
            #pragma unroll
            for (int ni = 0; ni < 4; ++ni) {
                const int col = n0 + wc * 64 + ni * 16 + c;
                Out[(size_t)m * EMBED + col] =
                    f2bf((acc[mi][ni][r] + bias[col]) * oscale);
            }
        }
}

// ---------------------------------------------------------------------------
// Output GEMM — unchanged from R3
// ---------------------------------------------------------------------------
__global__ __launch_bounds__(256)
void gemm_o_bf16(const unsigned short* __restrict__ A,
                 const unsigned short* __restrict__ Woh,
                 const float* __restrict__ bo,
                 float* __restrict__ C)
{
    __shared__ short As[128 * 32];
    __shared__ short Bs[64 * 32];

    const int tid  = threadIdx.x;
    const int lane = tid & 63;
    const int w    = tid >> 6;
    const int c    = lane & 15;
    const int g    = lane >> 4;
    const int wr   = w >> 1;
    const int wc   = w & 1;

    const int m0 = blockIdx.y * 128;
    const int n0 = blockIdx.x * 64;

    f32x4 acc[4][2] = {};

    for (int k0 = 0; k0 < EMBED; k0 += 32) {
        __syncthreads();
        #pragma unroll
        for (int i = 0; i < 2; ++i) {
            int s   = (w * 2 + i) * 64 + lane;
            int row = s >> 2;
            int k8  = (s & 3) * 8;
            gload_lds16(A + (size_t)(m0 + row) * EMBED + k0 + k8,
                        As + (size_t)(w * 2 + i) * 512);
        }
        {
            int s   = w * 64 + lane;
            int row = s >> 2;
            int k8  = (s & 3) * 8;
            gload_lds16(Woh + (size_t)(n0 + row) * EMBED + k0 + k8,
                        Bs + (size_t)w * 512);
        }
        __syncthreads();

        short8 af[4], bf[2];
        #pragma unroll
        for (int mi = 0; mi < 4; ++mi)
            af[mi] = *(const short8*)&As[(wr * 64 + mi * 16 + c) * 32 + g * 8];
        #pragma unroll
        for (int ni = 0; ni < 2; ++ni)
            bf[ni] = *(const short8*)&Bs[(wc * 32 + ni * 16 + c) * 32 + g * 8];
        #pragma unroll
        for (int mi = 0; mi < 4; ++mi)
            #pragma unroll
            for (int ni = 0; ni < 2; ++ni)
                acc[mi][ni] = __builtin_amdgcn_mfma_f32_16x16x32_bf16(
                    af[mi], bf[ni], acc[mi][ni], 0, 0, 0);
    }

    #pragma unroll
    for (int mi = 0; mi < 4; ++mi)
        #pragma unroll
        for (int r = 0; r < 4; ++r) {
            const int m = m0 + wr * 64 + mi * 16 + g * 4 + r;
            #pragma unroll
            for (int ni = 0; ni < 2; ++ni) {
                const int col = n0 + wc * 32 + ni * 16 + c;
                C[(size_t)m * EMBED + col] = acc[mi][ni][r] + bo[col];
            }
        }
}

// ---------------------------------------------------------------------------
// conv_vt: Vb bf16 [B*S][E] -> Vt bf16 [b][h][d][s] — unchanged from R3
// ---------------------------------------------------------------------------
__global__ __launch_bounds__(256)
void conv_vt_bf16(const unsigned short* __restrict__ Vb,
                  unsigned short* __restrict__ Vt)
{
    __shared__ unsigned short Ls[64][72];
    const int s0 = blockIdx.x * 64;
    const int h  = blockIdx.y;
    const int b  = blockIdx.z;
    const unsigned short* src = Vb + (size_t)(b * SEQ + s0) * EMBED + h * HDIM;

    #pragma unroll
    for (int it = 0; it < 2; ++it) {
        int slot = threadIdx.x + it * 256;
        int r = slot >> 3, c8 = (slot & 7) * 8;
        *(uint4*)&Ls[r][c8] = *(const uint4*)(src + (size_t)r * EMBED + c8);
    }
    __syncthreads();
    unsigned short* dst = Vt + ((size_t)(b * HEADS + h) * HDIM) * SEQ + s0;
    #pragma unroll
    for (int it = 0; it < 2; ++it) {
        int slot = threadIdx.x + it * 256;
        int d = slot >> 3, s8 = (slot & 7) * 8;
        unsigned short tmp[8] __attribute__((aligned(16)));
        #pragma unroll
        for (int j = 0; j < 8; ++j) tmp[j] = Ls[s8 + j][d];
        *(uint4*)(dst + (size_t)d * SEQ + s8) = *(const uint4*)tmp;
    }
}

// ---------------------------------------------------------------------------
// MFMA flash attention v2.
// Block = (128 q-rows, h, b): 4 waves x 32 q-rows (2 subtiles of 16).
// KV tile 64, double-buffered K/V staged via global_load_lds with
// rule-#21 swizzle: linear LDS dest, source chunk pre-XORed by (row&7),
// reads XOR the chunk back -> conflict-free ds_read_b128 (m214 geometry).
// Softmax: online, defer-max (T13, THR=8); P packed via v_cvt_pk_bf16_f32,
// routed through wave-private swizzled LDS.
// ---------------------------------------------------------------------------
__global__ __launch_bounds__(256)
void flash_attn_mfma2(const unsigned short* __restrict__ Qb,
                      const unsigned short* __restrict__ Kb,
                      const unsigned short* __restrict__ Vt,
                      unsigned short* __restrict__ O)
{
    __shared__ short KT[2][64 * 64];     // [buf][kv][d]  linear, swizzled content
    __shared__ short VT[2][64 * 64];     // [buf][d][kv]
    __shared__ short PT[4][32 * 64];     // per-wave P [q][kv]

    const int tid  = threadIdx.x;
    const int lane = tid & 63;
    const int w    = tid >> 6;
    const int c    = lane & 15;
    const int g    = lane >> 4;
    const int cm   = c & 7;              // read-side XOR key
    const int q0   = blockIdx.x * 128 + w * 32;
    const int h    = blockIdx.y;
    const int b    = blockIdx.z;

    // persistent Q B-frags: qf[qs][ks], col=q=c, k = ks*32 + g*8 + j
    short8 qf[2][2];
    #pragma unroll
    for (int qs = 0; qs < 2; ++qs) {
        const size_t r = (size_t)(b * SEQ + q0 + qs * 16 + c) * EMBED + h * HDIM;
        qf[qs][0] = *(const short8*)(Qb + r + g * 8);
        qf[qs][1] = *(const short8*)(Qb + r + 32 + g * 8);
    }

    // staging: wave w covers rows [w*16, w*16+16) via 2 instrs of 8 rows each.
    // lane l -> local row l>>3, linear chunk l&7; SOURCE chunk = (l&7)^(row&7).
    const int r0  = w * 16 + (lane >> 3);        // rows for instr 0
    const int r1  = r0 + 8;                      // rows for instr 1
    const int ch0 = (lane & 7) ^ (r0 & 7);
    const int ch1 = (lane & 7) ^ (r1 & 7);
    const unsigned short* kS0 = Kb + (size_t)(b * SEQ + r0) * EMBED + h * HDIM + ch0 * 8;
    const unsigned short* kS1 = Kb + (size_t)(b * SEQ + r1) * EMBED + h * HDIM + ch1 * 8;
    const unsigned short* vS0 = Vt + ((size_t)(b * HEADS + h) * HDIM + r0) * SEQ + ch0 * 8;
    const unsigned short* vS1 = Vt + ((size_t)(b * HEADS + h) * HDIM + r1) * SEQ + ch1 * 8;
    const int dst0 = (w * 2) * 512;              // wave-uniform LDS element offsets
    const int dst1 = (w * 2 + 1) * 512;

    f32x4 acc[2][4] = {};                        // [qs][dt], row=4g+r, col=d=16dt+c
    float m_run[2] = {-1e30f, -1e30f};
    float l_run[2] = {0.f, 0.f};

    // prologue: stage tile 0 into buf 0
    gload_lds16(kS0, &KT[0][dst0]);
    gload_lds16(kS1, &KT[0][dst1]);
    gload_lds16(vS0, &VT[0][dst0]);
    gload_lds16(vS1, &VT[0][dst1]);
    kS0 += (size_t)64 * EMBED; kS1 += (size_t)64 * EMBED;
    vS0 += 64; vS1 += 64;
    __syncthreads();                             // drains vmcnt(0)

    short* pw = &PT[w][0];

    for (int kt = 0; kt < SEQ / 64; ++kt) {
        const int bi = kt & 1;
        if (kt < SEQ / 64 - 1) {                 // issue next tile's async loads
            gload_lds16(kS0, &KT[bi ^ 1][dst0]);
            gload_lds16(kS1, &KT[bi ^ 1][dst1]);
            gload_lds16(vS0, &VT[bi ^ 1][dst0]);
            gload_lds16(vS1, &VT[bi ^ 1][dst1]);
            kS0 += (size_t)64 * EMBED; kS1 += (size_t)64 * EMBED;
            vS0 += 64; vS1 += 64;
        }

        // ---- QK^T: s[qs][t], C row = kv_local = 4g+r (+16t), col = q = c
        const short* kb_ = &KT[bi][0];
        f32x4 s[2][4] = {};
        #pragma unroll
        for (int t = 0; t < 4; ++t) {
            const int row = t * 16 + c;
            short8 ka0 = *(const short8*)&kb_[row * 64 + ((g)     ^ cm) * 8];
            short8 ka1 = *(const short8*)&kb_[row * 64 + ((4 + g) ^ cm) * 8];
            #pragma unroll
            for (int qs = 0; qs < 2; ++qs) {
                s[qs][t] = __builtin_amdgcn_mfma_f32_16x16x32_bf16(ka0, qf[qs][0], s[qs][t], 0, 0, 0);
                s[qs][t] = __builtin_amdgcn_mfma_f32_16x16x32_bf16(ka1, qf[qs][1], s[qs][t], 0, 0, 0);
            }
        }

        // ---- tile max per qs (over 16 in-lane + g across lanes)
        float mt[2];
        #pragma unroll
        for (int qs = 0; qs < 2; ++qs) {
            float a0 = fmaxf(fmaxf(s[qs][0][0], s[qs][0][1]), fmaxf(s[qs][0][2], s[qs][0][3]));
            float a1 = fmaxf(fmaxf(s[qs][1][0], s[qs][1][1]), fmaxf(s[qs][1][2], s[qs][1][3]));
            float a2 = fmaxf(fmaxf(s[qs][2][0], s[qs][2][1]), fmaxf(s[qs][2][2], s[qs][2][3]));
            float a3 = fmaxf(fmaxf(s[qs][3][0], s[qs][3][1]), fmaxf(s[qs][3][2], s[qs][3][3]));
            float m01 = fmaxf(fmaxf(a0, a1), fmaxf(a2, a3));
            m01 = fmaxf(m01, __shfl_xor(m01, 16, 64));
            m01 = fmaxf(m01, __shfl_xor(m01, 32, 64));
            mt[qs] = m01;
        }

        // ---- defer-max (T13): only rescale when max grew past THR=8
        const bool grow = (mt[0] > m_run[0] + 8.f) | (mt[1] > m_run[1] + 8.f);
        if (__any(grow ? 1 : 0)) {
            #pragma unroll
            for (int qs = 0; qs < 2; ++qs) {
                float mnew  = fmaxf(m_run[qs], mt[qs]);
                float alpha = __expf(m_run[qs] - mnew);
                m_run[qs] = mnew;
                l_run[qs] *= alpha;
                #pragma unroll
                for (int r = 0; r < 4; ++r) {
                    float af = __shfl(alpha, g * 4 + r, 64);
                    #pragma unroll
                    for (int dt = 0; dt < 4; ++dt)
                        acc[qs][dt][r] *= af;
                }
            }
        }

        // ---- P = exp(s - m), row-sum, pack bf16, write swizzled wave-private LDS
        #pragma unroll
        for (int qs = 0; qs < 2; ++qs) {
            const int prow = qs * 16 + c;
            float rs = 0.f;
            #pragma unroll
            for (int t = 0; t < 4; ++t) {
                float p0 = __expf(s[qs][t][0] - m_run[qs]);
                float p1 = __expf(s[qs][t][1] - m_run[qs]);
                float p2 = __expf(s[qs][t][2] - m_run[qs]);
                float p3 = __expf(s[qs][t][3] - m_run[qs]);
                rs += (p0 + p1) + (p2 + p3);
                uint2 u;
                u.x = pk_bf16(p0, p1);
                u.y = pk_bf16(p2, p3);
                // elements kv = 16t + 4g + 0..3 -> chunk 2t+(g>>1), half g&1
                const int chw = ((2 * t + (g >> 1)) ^ cm) * 8 + (g & 1) * 4;
                *(uint2*)&pw[prow * 64 + chw] = u;
            }
            rs += __shfl_xor(rs, 16, 64);
            rs += __shfl_xor(rs, 32, 64);
            l_run[qs] += rs;
        }

        asm volatile("" ::: "memory");           // order P reads after P writes

        // ---- PV: A = P (row=q=c), B = V (col=d=c); V frags shared across qs
        const short* vb_ = &VT[bi][0];
        short8 pa[2][2];
        #pragma unroll
        for (int qs = 0; qs < 2; ++qs) {
            const int prow = qs * 16 + c;
            pa[qs][0] = *(const short8*)&pw[prow * 64 + ((g)     ^ cm) * 8];
            pa[qs][1] = *(const short8*)&pw[prow * 64 + ((4 + g) ^ cm) * 8];
        }
        #pragma unroll
        for (int dt = 0; dt < 4; ++dt) {
            const int vrow = dt * 16 + c;
            short8 vb0 = *(const short8*)&vb_[vrow * 64 + ((g)     ^ cm) * 8];
            short8 vb1 = *(const short8*)&vb_[vrow * 64 + ((4 + g) ^ cm) * 8];
            #pragma unroll
            for (int qs = 0; qs < 2; ++qs) {
                acc[qs][dt] = __builtin_amdgcn_mfma_f32_16x16x32_bf16(pa[qs][0], vb0, acc[qs][dt], 0, 0, 0);
                acc[qs][dt] = __builtin_amdgcn_mfma_f32_16x16x32_bf16(pa[qs][1], vb1, acc[qs][dt], 0, 0, 0);
            }
        }

        __syncthreads();   // drains this iter's prefetch; all waves done with buf bi
    }

    // ---- epilogue
    #pragma unroll
    for (int qs = 0; qs < 2; ++qs) {
        float rl = 1.f / l_run[qs];
        const size_t ob = (size_t)(b * SEQ + q0 + qs * 16) * EMBED + h * HDIM;
        #pragma unroll
        for (int r = 0; r < 4; ++r) {
            float rf = __shfl(rl, g * 4 + r, 64);
            #pragma unroll
            for (int dt = 0; dt < 4; ++dt)
                O[ob + (size_t)(g * 4 + r) * EMBED + dt * 16 + c] =
                    f2bf(acc[qs][dt][r] * rf);
        }
    }
}

// ---------------------------------------------------------------------------
extern "C" void kernel_launch(void* const* d_in, const int* in_sizes, int n_in,
                              void* d_out, int out_size, void* d_ws, size_t ws_size,
                              hipStream_t stream)
{
    const float* x  = (const float*)d_in[0];
    const float* Wq = (const float*)d_in[1];
    const float* bq = (const float*)d_in[2];
    const float* Wk = (const float*)d_in[3];
    const float* bk = (const float*)d_in[4];
    const float* Wv = (const float*)d_in[5];
    const float* bv = (const float*)d_in[6];
    const float* Wo = (const float*)d_in[7];
    const float* bo = (const float*)d_in[8];
    float* out = (float*)d_out;

    const size_t ME = (size_t)MTOT * EMBED;
    unsigned short* xh   = (unsigned short*)d_ws;
    unsigned short* Qb   = xh   + ME;
    unsigned short* Kb   = Qb   + ME;
    unsigned short* Vb   = Kb   + ME;
    unsigned short* Vt   = Vb   + ME;
    unsigned short* attn = Vt   + ME;
    unsigned short* Wh   = attn + ME;

    dim3 blk(256);

    convx<<<dim3(MTOT * EMBED / 2048), blk, 0, stream>>>(x, xh);
    convw<<<dim3(EMBED * EMBED / 1024, 4), blk, 0, stream>>>(Wq, Wk, Wv, Wo, Wh);

    gemm_qkv_bf16<<<dim3(24, MTOT / 128), blk, 0, stream>>>(
        xh, Wh, Wh + (size_t)EMBED * EMBED, Wh + 2 * (size_t)EMBED * EMBED,
        bq, bk, bv, Qb, Kb, Vb);

    conv_vt_bf16<<<dim3(SEQ / 64, HEADS, BATCH), blk, 0, stream>>>(Vb, Vt);

    flash_attn_mfma2<<<dim3(SEQ / 128, HEADS, BATCH), blk, 0, stream>>>(Qb, Kb, Vt, attn);

    gemm_o_bf16<<<dim3(EMBED / 64, MTOT / 128), blk, 0, stream>>>(
        attn, Wh + 3 * (size_t)EMBED * EMBED, bo, out);
}

// Round 5
// 133.784 us; speedup vs baseline: 9.0591x; 1.0378x over previous
//
#include <hip/hip_runtime.h>
#include <cstddef>

#define EMBED 1024
#define HEADS 16
#define HDIM  64
#define BATCH 2
#define SEQ   2048
#define MTOT  (BATCH*SEQ)

typedef __attribute__((ext_vector_type(8)))  short short8;   // 8 bf16 = 4 VGPRs
typedef __attribute__((ext_vector_type(4)))  float f32x4;    // 16x16 C/D frag
typedef __attribute__((ext_vector_type(16))) float f32x16;   // 32x32 C/D frag

typedef __attribute__((address_space(1))) const unsigned int* gas_u32p;
typedef __attribute__((address_space(3))) unsigned int* las_u32p;

// async global->LDS, 16B per lane; LDS dest = wave-uniform base + lane*16
static __device__ __forceinline__ void gload_lds16(const void* g, void* l) {
    __builtin_amdgcn_global_load_lds((gas_u32p)g, (las_u32p)l, 16, 0, 0);
}

// fp32 -> bf16 round-to-nearest-even
static __device__ __forceinline__ unsigned short f2bf(float x) {
    unsigned u = __builtin_bit_cast(unsigned, x);
    unsigned r = (u + 0x7FFFu + ((u >> 16) & 1u)) >> 16;
    return (unsigned short)r;
}

// pack two fp32 -> one u32 of 2 bf16 (hardware cvt)
static __device__ __forceinline__ unsigned pk_bf16(float lo, float hi) {
    unsigned r;
    asm("v_cvt_pk_bf16_f32 %0, %1, %2" : "=v"(r) : "v"(lo), "v"(hi));
    return r;
}

// swap: a' = {a.lo-lanes | b.lo-lanes}, b' = {a.hi-lanes | b.hi-lanes}
static __device__ __forceinline__ void plane32_swap(unsigned &a, unsigned &b) {
    auto r = __builtin_amdgcn_permlane32_swap((int)a, (int)b, false, false);
    a = (unsigned)r[0];
    b = (unsigned)r[1];
}

static __device__ __forceinline__ f32x16 mfma32(short8 a, short8 b, f32x16 c) {
    return __builtin_amdgcn_mfma_f32_32x32x16_bf16(a, b, c, 0, 0, 0);
}

// ---------------------------------------------------------------------------
// convx: x fp32 -> bf16 (8 elems/thread)
// ---------------------------------------------------------------------------
__global__ __launch_bounds__(256)
void convx(const float* __restrict__ x, unsigned short* __restrict__ xh)
{
    const size_t i = ((size_t)blockIdx.x * 256 + threadIdx.x) * 8;
    float4 a = *(const float4*)(x + i);
    float4 b = *(const float4*)(x + i + 4);
    unsigned short o[8] __attribute__((aligned(16)));
    o[0] = f2bf(a.x); o[1] = f2bf(a.y); o[2] = f2bf(a.z); o[3] = f2bf(a.w);
    o[4] = f2bf(b.x); o[5] = f2bf(b.y); o[6] = f2bf(b.z); o[7] = f2bf(b.w);
    *(uint4*)(xh + i) = *(const uint4*)o;
}

// ---------------------------------------------------------------------------
// convw: {Wq,Wk,Wv,Wo} fp32 -> packed bf16 Wh[sel][1M]
// ---------------------------------------------------------------------------
__global__ __launch_bounds__(256)
void convw(const float* __restrict__ Wq, const float* __restrict__ Wk,
           const float* __restrict__ Wv, const float* __restrict__ Wo,
           unsigned short* __restrict__ Wh)
{
    const int sel = blockIdx.y;
    const float* src = sel == 0 ? Wq : sel == 1 ? Wk : sel == 2 ? Wv : Wo;
    unsigned short* dst = Wh + (size_t)sel * EMBED * EMBED;
    const size_t i = ((size_t)blockIdx.x * 256 + threadIdx.x) * 4;
    float4 a = *(const float4*)(src + i);
    ushort4 o;
    o.x = f2bf(a.x); o.y = f2bf(a.y); o.z = f2bf(a.z); o.w = f2bf(a.w);
    *(ushort4*)(dst + i) = o;
}

// ---------------------------------------------------------------------------
// Fused QKV GEMM (bf16 MFMA). V output written directly transposed to
// Vt[b][h][d][s] (kills the conv_vt pass). Q pre-scaled by 0.125.
// ---------------------------------------------------------------------------
__global__ __launch_bounds__(256)
void gemm_qkv_bf16(const unsigned short* __restrict__ A,
                   const unsigned short* __restrict__ Wqh,
                   const unsigned short* __restrict__ Wkh,
                   const unsigned short* __restrict__ Wvh,
                   const float* __restrict__ bq,
                   const float* __restrict__ bk,
                   const float* __restrict__ bv,
                   unsigned short* __restrict__ Qb,
                   unsigned short* __restrict__ Kb,
                   unsigned short* __restrict__ Vt)
{
    __shared__ short As[128 * 32];
    __shared__ short Bs[128 * 32];

    const int tid  = threadIdx.x;
    const int lane = tid & 63;
    const int w    = tid >> 6;
    const int c    = lane & 15;
    const int g    = lane >> 4;
    const int wr   = w >> 1;
    const int wc   = w & 1;

    const int m0   = blockIdx.y * 128;
    const int bx   = blockIdx.x;
    const int wsel = bx >> 3;
    const int n0   = (bx & 7) * 128;

    const unsigned short* W = (wsel == 0) ? Wqh : (wsel == 1) ? Wkh : Wvh;
    const float* bias       = (wsel == 0) ? bq  : (wsel == 1) ? bk  : bv;

    f32x4 acc[4][4] = {};

    for (int k0 = 0; k0 < EMBED; k0 += 32) {
        __syncthreads();
        #pragma unroll
        for (int i = 0; i < 2; ++i) {
            int s   = (w * 2 + i) * 64 + lane;
            int row = s >> 2;
            int k8  = (s & 3) * 8;
            gload_lds16(A + (size_t)(m0 + row) * EMBED + k0 + k8,
                        As + (size_t)(w * 2 + i) * 512);
            gload_lds16(W + (size_t)(n0 + row) * EMBED + k0 + k8,
                        Bs + (size_t)(w * 2 + i) * 512);
        }
        __syncthreads();

        short8 af[4], bf[4];
        #pragma unroll
        for (int mi = 0; mi < 4; ++mi)
            af[mi] = *(const short8*)&As[(wr * 64 + mi * 16 + c) * 32 + g * 8];
        #pragma unroll
        for (int ni = 0; ni < 4; ++ni)
            bf[ni] = *(const short8*)&Bs[(wc * 64 + ni * 16 + c) * 32 + g * 8];
        #pragma unroll
        for (int mi = 0; mi < 4; ++mi)
            #pragma unroll
            for (int ni = 0; ni < 4; ++ni)
                acc[mi][ni] = __builtin_amdgcn_mfma_f32_16x16x32_bf16(
                    af[mi], bf[ni], acc[mi][ni], 0, 0, 0);
    }

    if (wsel == 2) {
        // V: write transposed Vt[((b*H+h)*64+d)*SEQ + s], 4 consecutive s / store
        #pragma unroll
        for (int mi = 0; mi < 4; ++mi) {
            const int m  = m0 + wr * 64 + mi * 16 + g * 4;   // s base (4 rows)
            const int bb = m >> 11;
            const int ss = m & (SEQ - 1);
            #pragma unroll
            for (int ni = 0; ni < 4; ++ni) {
                const int col = n0 + wc * 64 + ni * 16 + c;  // h*64 + d
                const int hh = col >> 6, dd = col & 63;
                const float bi_ = bias[col];
                ushort4 o;
                o.x = f2bf(acc[mi][ni][0] + bi_);
                o.y = f2bf(acc[mi][ni][1] + bi_);
                o.z = f2bf(acc[mi][ni][2] + bi_);
                o.w = f2bf(acc[mi][ni][3] + bi_);
                *(ushort4*)&Vt[((size_t)((bb * HEADS + hh) * HDIM) + dd) * SEQ + ss] = o;
            }
        }
    } else {
        unsigned short* Out = (wsel == 0) ? Qb : Kb;
        const float oscale  = (wsel == 0) ? 0.125f : 1.0f;
        #pragma unroll
        for (int mi = 0; mi < 4; ++mi)
            #pragma unroll
            for (int r = 0; r < 4; ++r) {
                const int m = m0 + wr * 64 + mi * 16 + g * 4 + r;
                #pragma unroll
                for (int ni = 0; ni < 4; ++ni) {
                    const int col = n0 + wc * 64 + ni * 16 + c;
                    Out[(size_t)m * EMBED + col] =
                        f2bf((acc[mi][ni][r] + bias[col]) * oscale);
                }
            }
    }
}

// ---------------------------------------------------------------------------
// Output GEMM — unchanged
// ---------------------------------------------------------------------------
__global__ __launch_bounds__(256)
void gemm_o_bf16(const unsigned short* __restrict__ A,
                 const unsigned short* __restrict__ Woh,
                 const float* __restrict__ bo,
                 float* __restrict__ C)
{
    __shared__ short As[128 * 32];
    __shared__ short Bs[64 * 32];

    const int tid  = threadIdx.x;
    const int lane = tid & 63;
    const int w    = tid >> 6;
    const int c    = lane & 15;
    const int g    = lane >> 4;
    const int wr   = w >> 1;
    const int wc   = w & 1;

    const int m0 = blockIdx.y * 128;
    const int n0 = blockIdx.x * 64;

    f32x4 acc[4][2] = {};

    for (int k0 = 0; k0 < EMBED; k0 += 32) {
        __syncthreads();
        #pragma unroll
        for (int i = 0; i < 2; ++i) {
            int s   = (w * 2 + i) * 64 + lane;
            int row = s >> 2;
            int k8  = (s & 3) * 8;
            gload_lds16(A + (size_t)(m0 + row) * EMBED + k0 + k8,
                        As + (size_t)(w * 2 + i) * 512);
        }
        {
            int s   = w * 64 + lane;
            int row = s >> 2;
            int k8  = (s & 3) * 8;
            gload_lds16(Woh + (size_t)(n0 + row) * EMBED + k0 + k8,
                        Bs + (size_t)w * 512);
        }
        __syncthreads();

        short8 af[4], bf[2];
        #pragma unroll
        for (int mi = 0; mi < 4; ++mi)
            af[mi] = *(const short8*)&As[(wr * 64 + mi * 16 + c) * 32 + g * 8];
        #pragma unroll
        for (int ni = 0; ni < 2; ++ni)
            bf[ni] = *(const short8*)&Bs[(wc * 32 + ni * 16 + c) * 32 + g * 8];
        #pragma unroll
        for (int mi = 0; mi < 4; ++mi)
            #pragma unroll
            for (int ni = 0; ni < 2; ++ni)
                acc[mi][ni] = __builtin_amdgcn_mfma_f32_16x16x32_bf16(
                    af[mi], bf[ni], acc[mi][ni], 0, 0, 0);
    }

    #pragma unroll
    for (int mi = 0; mi < 4; ++mi)
        #pragma unroll
        for (int r = 0; r < 4; ++r) {
            const int m = m0 + wr * 64 + mi * 16 + g * 4 + r;
            #pragma unroll
            for (int ni = 0; ni < 2; ++ni) {
                const int col = n0 + wc * 32 + ni * 16 + c;
                C[(size_t)m * EMBED + col] = acc[mi][ni][r] + bo[col];
            }
        }
}

// ---------------------------------------------------------------------------
// MFMA flash attention v3: 32x32x16 MFMA, in-register P, KV-split-2.
// Block = 512 thr (8 waves): wave w -> q-subtile (w&3)*32, kv-half w>>2.
// Per wave: 32 q rows, kv tiles of 64 over its half (16 iters).
//   QK^T: s[t] (t = kv subtile of 32) = mfma(K, Q); C: col=lane&31=q,
//         row(kv) = (reg&3)+8*(reg>>2)+4*(lane>>5)   [m74/m101 layout]
//   softmax: in-lane over 32 regs + shfl_xor(32); defer-max THR=8 (T13)
//   P -> A-frags purely in-register: cvt_pk pairs + permlane32_swap (T12)
//   PV: acc[dt] += mfma(P, V) from swizzled VT tiles
// K/V staged via global_load_lds, double-buffered, rule-#21 XOR swizzle.
// End: lo/hi halves merged via LDS (exact fp32 flash merge).
// ---------------------------------------------------------------------------
__global__ __launch_bounds__(512, 4)
void flash_attn_mfma3(const unsigned short* __restrict__ Qb,
                      const unsigned short* __restrict__ Kb,
                      const unsigned short* __restrict__ Vt,
                      unsigned short* __restrict__ O)
{
    __shared__ short KT[2][2][64 * 64];   // [half][buf][kv][d]  (swizzled chunks)
    __shared__ short VT[2][2][64 * 64];   // [half][buf][d][kv]

    const int tid  = threadIdx.x;
    const int lane = tid & 63;
    const int w    = tid >> 6;            // 0..7
    const int qt   = w & 3;               // q subtile
    const int half = w >> 2;              // kv half
    const int l31  = lane & 31;
    const int hi   = lane >> 5;
    const int q0   = blockIdx.x * 128 + qt * 32;
    const int h    = blockIdx.y;
    const int b    = blockIdx.z;

    // persistent Q B-frags: qf[kc] holds Q[q=l31][d = kc*16 + hi*8 + j]
    short8 qf[4];
    {
        const unsigned short* qrow =
            Qb + (size_t)(b * SEQ + q0 + l31) * EMBED + h * HDIM + hi * 8;
        #pragma unroll
        for (int kc = 0; kc < 4; ++kc)
            qf[kc] = *(const short8*)(qrow + kc * 16);
    }

    // staging assignment: tile tb = w>>1 (0=K_lo,1=V_lo,2=K_hi,3=V_hi),
    // slice-group ssub = w&1 (rows ssub*32..+31). Source chunk pre-XORed
    // by row&7 (invariant across the 4 slices).
    const int tb     = w >> 1;
    const int sthalf = tb >> 1;
    const int stV    = tb & 1;
    const int ssub   = w & 1;
    const int strow  = ssub * 32 + (lane >> 3);
    const int ch     = (lane & 7) ^ (strow & 7);
    const unsigned short* kS =
        Kb + (size_t)(b * SEQ + sthalf * (SEQ / 2) + strow) * EMBED + h * HDIM + ch * 8;
    const unsigned short* vS =
        Vt + ((size_t)((b * HEADS + h) * HDIM) + strow) * SEQ + sthalf * (SEQ / 2) + ch * 8;

    f32x16 acc[2] = {};
    float m_run = -1e30f, l_run = 0.f;

    #define STAGE(kt2, bb)                                                    \
        do {                                                                  \
            if (stV == 0) {                                                   \
                const unsigned short* src = kS + (size_t)(kt2) * 64 * EMBED;  \
                short* kd = &KT[sthalf][bb][ssub * 2048];                     \
                _Pragma("unroll")                                             \
                for (int it = 0; it < 4; ++it)                                \
                    gload_lds16(src + (size_t)it * 8 * EMBED, kd + it * 512); \
            } else {                                                          \
                const unsigned short* src = vS + (kt2) * 64;                  \
                short* vd = &VT[sthalf][bb][ssub * 2048];                     \
                _Pragma("unroll")                                             \
                for (int it = 0; it < 4; ++it)                                \
                    gload_lds16(src + (size_t)it * 8 * SEQ, vd + it * 512);   \
            }                                                                 \
        } while (0)

    STAGE(0, 0);
    __syncthreads();

    for (int kt = 0; kt < SEQ / 2 / 64; ++kt) {
        const int bi = kt & 1;
        if (kt < SEQ / 2 / 64 - 1) STAGE(kt + 1, bi ^ 1);

        const short* kb_ = &KT[half][bi][0];
        const short* vb_ = &VT[half][bi][0];

        // ---- QK^T
        f32x16 s[2] = {};
        #pragma unroll
        for (int t = 0; t < 2; ++t) {
            const int row = t * 32 + l31;
            const int rm  = l31 & 7;
            #pragma unroll
            for (int kc = 0; kc < 4; ++kc) {
                short8 ka = *(const short8*)&kb_[row * 64 + (((2 * kc + hi) ^ rm) * 8)];
                s[t] = mfma32(ka, qf[kc], s[t]);
            }
        }

        // ---- tile max (per q = l31)
        float mt = -1e30f;
        #pragma unroll
        for (int t = 0; t < 2; ++t)
            #pragma unroll
            for (int r = 0; r < 16; ++r)
                mt = fmaxf(mt, s[t][r]);
        mt = fmaxf(mt, __shfl_xor(mt, 32, 64));

        // ---- defer-max rescale (T13, THR=8)
        if (__any(mt > m_run + 8.f)) {
            float mnew  = fmaxf(m_run, mt);
            float alpha = __expf(m_run - mnew);
            m_run = mnew;
            l_run *= alpha;
            #pragma unroll
            for (int r = 0; r < 16; ++r) {
                const int qr = (r & 3) + 8 * (r >> 2) + 4 * hi;
                float af = __shfl(alpha, qr, 64);
                acc[0][r] *= af;
                acc[1][r] *= af;
            }
        }

        // ---- P = exp(s - m) in place, row-sum
        float rs = 0.f;
        #pragma unroll
        for (int t = 0; t < 2; ++t)
            #pragma unroll
            for (int r = 0; r < 16; ++r) {
                float pv = __expf(s[t][r] - m_run);
                s[t][r] = pv;
                rs += pv;
            }
        rs += __shfl_xor(rs, 32, 64);
        l_run += rs;

        // ---- P -> A-frags in-register (cvt_pk + permlane32_swap)
        short8 pf[2][2];
        #pragma unroll
        for (int t = 0; t < 2; ++t)
            #pragma unroll
            for (int kc = 0; kc < 2; ++kc) {
                unsigned A0 = pk_bf16(s[t][8 * kc + 0], s[t][8 * kc + 1]);
                unsigned A1 = pk_bf16(s[t][8 * kc + 2], s[t][8 * kc + 3]);
                unsigned B0 = pk_bf16(s[t][8 * kc + 4], s[t][8 * kc + 5]);
                unsigned B1 = pk_bf16(s[t][8 * kc + 6], s[t][8 * kc + 7]);
                plane32_swap(A0, B0);
                plane32_swap(A1, B1);
                uint4 fw = make_uint4(A0, A1, B0, B1);
                pf[t][kc] = __builtin_bit_cast(short8, fw);
            }

        // ---- PV
        #pragma unroll
        for (int dt = 0; dt < 2; ++dt) {
            const int row = dt * 32 + l31;
            const int rm  = l31 & 7;
            #pragma unroll
            for (int t = 0; t < 2; ++t)
                #pragma unroll
                for (int kc = 0; kc < 2; ++kc) {
                    short8 vf = *(const short8*)
                        &vb_[row * 64 + (((4 * t + 2 * kc + hi) ^ rm) * 8)];
                    acc[dt] = mfma32(pf[t][kc], vf, acc[dt]);
                }
        }

        __syncthreads();
    }
    #undef STAGE

    // ---- merge kv-halves (overlay scratch on KT/VT) ----
    float* mrgf = (float*)&KT[0][0][0];   // 4 pairs x 32q x 64d fp32 = 32KB
    float* mlbf = (float*)&VT[0][0][0];   // 4 pairs x 32q x {m,l}
    if (half == 1) {
        #pragma unroll
        for (int dt = 0; dt < 2; ++dt)
            #pragma unroll
            for (int r = 0; r < 16; ++r) {
                const int qr = (r & 3) + 8 * (r >> 2) + 4 * hi;
                mrgf[qt * 2048 + qr * 64 + dt * 32 + l31] = acc[dt][r];
            }
        if (lane < 32) {
            *(float2*)&mlbf[qt * 64 + lane * 2] = make_float2(m_run, l_run);
        }
    }
    __syncthreads();
    if (half == 0) {
        float2 ml = *(const float2*)&mlbf[qt * 64 + l31 * 2];
        float mx  = fmaxf(m_run, ml.x);
        float al  = __expf(m_run - mx);
        float ah  = __expf(ml.x - mx);
        float inv = 1.f / (l_run * al + ml.y * ah);
        float fl = al * inv, fh = ah * inv;
        #pragma unroll
        for (int r = 0; r < 16; ++r) {
            const int qr = (r & 3) + 8 * (r >> 2) + 4 * hi;
            float flr = __shfl(fl, qr, 64);
            float fhr = __shfl(fh, qr, 64);
            #pragma unroll
            for (int dt = 0; dt < 2; ++dt) {
                float oh  = mrgf[qt * 2048 + qr * 64 + dt * 32 + l31];
                float val = acc[dt][r] * flr + oh * fhr;
                O[(size_t)(b * SEQ + q0 + qr) * EMBED + h * HDIM + dt * 32 + l31]
                    = f2bf(val);
            }
        }
    }
}

// ---------------------------------------------------------------------------
extern "C" void kernel_launch(void* const* d_in, const int* in_sizes, int n_in,
                              void* d_out, int out_size, void* d_ws, size_t ws_size,
                              hipStream_t stream)
{
    const float* x  = (const float*)d_in[0];
    const float* Wq = (const float*)d_in[1];
    const float* bq = (const float*)d_in[2];
    const float* Wk = (const float*)d_in[3];
    const float* bk = (const float*)d_in[4];
    const float* Wv = (const float*)d_in[5];
    const float* bv = (const float*)d_in[6];
    const float* Wo = (const float*)d_in[7];
    const float* bo = (const float*)d_in[8];
    float* out = (float*)d_out;

    const size_t ME = (size_t)MTOT * EMBED;
    unsigned short* xh   = (unsigned short*)d_ws;     // 8 MB each
    unsigned short* Qb   = xh   + ME;
    unsigned short* Kb   = Qb   + ME;
    unsigned short* Vt   = Kb   + ME;                 // [b][h][d][s]
    unsigned short* attn = Vt   + ME;
    unsigned short* Wh   = attn + ME;                 // 4 x 2 MB packed

    dim3 blk(256);

    convx<<<dim3(MTOT * EMBED / 2048), blk, 0, stream>>>(x, xh);
    convw<<<dim3(EMBED * EMBED / 1024, 4), blk, 0, stream>>>(Wq, Wk, Wv, Wo, Wh);

    gemm_qkv_bf16<<<dim3(24, MTOT / 128), blk, 0, stream>>>(
        xh, Wh, Wh + (size_t)EMBED * EMBED, Wh + 2 * (size_t)EMBED * EMBED,
        bq, bk, bv, Qb, Kb, Vt);

    flash_attn_mfma3<<<dim3(SEQ / 128, HEADS, BATCH), dim3(512), 0, stream>>>(
        Qb, Kb, Vt, attn);

    gemm_o_bf16<<<dim3(EMBED / 64, MTOT / 128), blk, 0, stream>>>(
        attn, Wh + 3 * (size_t)EMBED * EMBED, bo, out);
}